// Round 7
// baseline (577.185 us; speedup 1.0000x reference)
//
#include <hip/hip_runtime.h>
#include <math.h>

#define LSEQ 1024
#define NB 16
#define NC 12
#define NH 256
#define NM 32
#define NS 3
#define TWO_PI 6.283185307179586f

#define PSTR  196608     // P plane stride (3*256*256)
#define VPSTR 786432     // V plane stride (3*256*1024)

// ---- workspace layout (float offsets) ----
#define OFF_MEANS 0            // 192
#define OFF_STDEV 192          // 192
#define OFF_EPART 384          // 24576
#define OFF_WT_RE 24960        // 24576
#define OFF_WT_IM 49536        // 24576
#define OFF_VP    74112        // 4 planes x 786432 = 3145728
#define OFF_V     3219840      // 786432 (dense)
#define OFF_PP0   4006272      // 786432 (4 planes x 196608)
#define OFF_PP1   4792704      // 786432
#define OFF_H     5579136      // 1024

__device__ __forceinline__ float block_reduce_sum(float v, float* sbuf) {
  int t = threadIdx.x;
  sbuf[t] = v; __syncthreads();
  for (int off = 128; off > 0; off >>= 1) {
    if (t < off) sbuf[t] += sbuf[t + off];
    __syncthreads();
  }
  float r = sbuf[0];
  __syncthreads();
  return r;
}

// front: stats (0..191) | epart (192..287) | Vp col0 init (288) | H/out init (289)
__global__ __launch_bounds__(256) void k_front(const float* __restrict__ x,
                                               const float* __restrict__ Bv,
                                               const float* __restrict__ ev,
                                               const float* __restrict__ b_fc,
                                               float* __restrict__ means,
                                               float* __restrict__ stdev,
                                               float* __restrict__ epart,
                                               float* __restrict__ Vp,
                                               float* __restrict__ H,
                                               float* __restrict__ out) {
  __shared__ float smem[1280];
  int blk = blockIdx.x;
  int t = threadIdx.x;
  if (blk < 192) {
    int b = blk / NC, c = blk % NC;
    float* xs = smem;
    float* red = smem + 1024;
    for (int e = 0; e < 4; ++e) {
      int tau = t + 256 * e;
      xs[tau] = x[((size_t)b * LSEQ + tau) * NC + c];
    }
    __syncthreads();
    float p = 0.f;
    for (int e = 0; e < 4; ++e) p += xs[t + 256 * e];
    float sum = block_reduce_sum(p, red);
    float mean = sum * (1.0f / LSEQ);
    float q = 0.f;
    for (int e = 0; e < 4; ++e) { float d = xs[t + 256 * e] - mean; q += d * d; }
    float sq = block_reduce_sum(q, red);
    if (t == 0) {
      means[blk] = mean;
      stdev[blk] = sqrtf(sq * (1.0f / LSEQ) + 1e-5f);
    }
  } else if (blk < 288) {
    int bb = blk - 192;          // s*32 + chunk
    int s = bb >> 5, ch = bb & 31;
    float acc = 0.f;
    const float* base = ev + (size_t)s * LSEQ * NH + (size_t)ch * 32 * NH + t;
    for (int l = 0; l < 32; ++l) acc += base[(size_t)l * NH];
    epart[(size_t)bb * NH + t] = acc;
  } else if (blk == 288) {
    // col 0 of each plane: plane0 = B, planes 1-3 = 0
    for (int pl = 0; pl < 4; ++pl)
      for (int row = t; row < 768; row += 256)
        Vp[(size_t)pl * VPSTR + (size_t)row * LSEQ] = (pl == 0) ? Bv[row] : 0.0f;
  } else {
    for (int e = 0; e < 4; ++e) H[t + 256 * e] = 0.0f;
    if (t < NB * 5) out[t] = b_fc[t % 5];
  }
}

// standalone wtilde: 768 blocks, one (s,i) each; float4 streaming of w_spec.
// wt[s,k,i] = sum_o ebar[s,o] * w[s,i,o,k]
__global__ __launch_bounds__(256) void k_wtilde(const float* __restrict__ wre,
                                                const float* __restrict__ wim,
                                                const float* __restrict__ epart,
                                                float* __restrict__ wt_re,
                                                float* __restrict__ wt_im) {
  int blk = blockIdx.x; int s = blk / NH, i = blk % NH;
  int t = threadIdx.x;
  __shared__ float ebs[NH];
  __shared__ float sr[1024], si2[1024];
  float eb = 0.f;
  for (int ch = 0; ch < 32; ++ch) eb += epart[(s * 32 + ch) * 256 + t];
  ebs[t] = eb * (1.0f / LSEQ);
  __syncthreads();
  const float* br = wre + (size_t)(s * NH + i) * NH * NM;
  const float* bi = wim + (size_t)(s * NH + i) * NH * NM;
  // element index o*32+k decomposes as (t*4 + 1024*it) + j ; o = t>>3 + 32*it, k = (t&7)*4 + j
  float aR[4] = {0.f, 0.f, 0.f, 0.f}, aI[4] = {0.f, 0.f, 0.f, 0.f};
  #pragma unroll
  for (int it = 0; it < 8; ++it) {
    int o = (t >> 3) + 32 * it;
    float e = ebs[o];
    float4 vr = *(const float4*)(br + (size_t)t * 4 + 1024 * it);
    float4 vi = *(const float4*)(bi + (size_t)t * 4 + 1024 * it);
    aR[0] += e * vr.x; aR[1] += e * vr.y; aR[2] += e * vr.z; aR[3] += e * vr.w;
    aI[0] += e * vi.x; aI[1] += e * vi.y; aI[2] += e * vi.z; aI[3] += e * vi.w;
  }
  // partial for k = (t&7)*4+j from o-group (t>>3) lives at sr[(t>>3)*32 + (t&7)*4 + j] = sr[t*4+j]
  *(float4*)(sr + t * 4)  = make_float4(aR[0], aR[1], aR[2], aR[3]);
  *(float4*)(si2 + t * 4) = make_float4(aI[0], aI[1], aI[2], aI[3]);
  __syncthreads();
  if (t < 32) {
    float r = 0.f, im = 0.f;
    #pragma unroll
    for (int og = 0; og < 32; ++og) { r += sr[og * 32 + t]; im += si2[og * 32 + t]; }
    wt_re[(size_t)(s * NM + t) * NH + i] = r;
    wt_im[(size_t)(s * NM + t) * NH + i] = im;
  }
}

#define FMA_ROW(r, av) { acc[r][0] += (av)*b4.x; acc[r][1] += (av)*b4.y; acc[r][2] += (av)*b4.z; acc[r][3] += (av)*b4.w; }

// 128x64 output tile, K-slice of 64 (2 chunks of 32). 256 threads, 8x4 acc/thread.
// A/B inputs may be carried as plane-partials summed during staging; dense output.
__device__ void gemm64(float* As, float* Bs,
                       const float* Abase, int anp, int apstr,
                       const float* Bbase, int bnp, int bpstr, int bld, int colLimit,
                       int rowbase, int colbase, int kb0,
                       float* outp, int outld, int outcol0, int outColLim) {
  const int tid = threadIdx.x;
  const int tx = tid & 15, ty = tid >> 4;
  const int kkA = tid & 31, rA = tid >> 5;
  const int jB = tid & 63, kB = tid >> 6;
  float acc[8][4];
  #pragma unroll
  for (int i = 0; i < 8; ++i)
    #pragma unroll
    for (int j = 0; j < 4; ++j) acc[i][j] = 0.f;

  for (int ch = 0; ch < 2; ++ch) {
    int kb = kb0 + ch * 32;
    #pragma unroll
    for (int p = 0; p < 16; ++p) {
      int row = rowbase + rA + 8 * p;
      float v = 0.f;
      for (int pp = 0; pp < anp; ++pp) v += Abase[(size_t)pp * apstr + (size_t)row * 256 + kb + kkA];
      As[kkA * 132 + rA + 8 * p] = v;
    }
    #pragma unroll
    for (int q = 0; q < 8; ++q) {
      int kk = kB + 4 * q;
      int j = colbase + jB;
      float v = 0.f;
      if (j < colLimit) {
        for (int pp = 0; pp < bnp; ++pp) v += Bbase[(size_t)pp * bpstr + (size_t)(kb + kk) * bld + j];
      }
      Bs[kk * 68 + jB] = v;
    }
    __syncthreads();
    #pragma unroll
    for (int kk = 0; kk < 32; ++kk) {
      float4 b4 = *(const float4*)(Bs + kk * 68 + tx * 4);
      float4 a0 = *(const float4*)(As + kk * 132 + ty * 8);
      float4 a1 = *(const float4*)(As + kk * 132 + ty * 8 + 4);
      FMA_ROW(0, a0.x) FMA_ROW(1, a0.y) FMA_ROW(2, a0.z) FMA_ROW(3, a0.w)
      FMA_ROW(4, a1.x) FMA_ROW(5, a1.y) FMA_ROW(6, a1.z) FMA_ROW(7, a1.w)
    }
    __syncthreads();
  }
  if (colbase + 64 <= outColLim) {
    #pragma unroll
    for (int i = 0; i < 8; ++i) {
      int row = rowbase + ty * 8 + i;
      float4 st; st.x = acc[i][0]; st.y = acc[i][1]; st.z = acc[i][2]; st.w = acc[i][3];
      *(float4*)(outp + (size_t)row * outld + outcol0 + colbase + tx * 4) = st;
    }
  } else {
    #pragma unroll
    for (int i = 0; i < 8; ++i) {
      int row = rowbase + ty * 8 + i;
      #pragma unroll
      for (int j = 0; j < 4; ++j) {
        int c = colbase + tx * 4 + j;
        if (c < outColLim) outp[(size_t)row * outld + outcol0 + c] = acc[i][j];
      }
    }
  }
}

// one chain stage: squares (split-K4 -> P planes) | extends (split-K4 -> V planes)
__global__ __launch_bounds__(256) void k_chain(const float* __restrict__ Pc,
                                               float* __restrict__ Pn,
                                               float* __restrict__ Vp,
                                               int m, int anp, int nSq, int ntct) {
  __shared__ float smem[6608];
  float* As = smem;            // [32][132]
  float* Bs = smem + 4224;     // [32][68]
  const int blk = blockIdx.x;
  if (blk < nSq) {
    int slice = blk & 3, rest = blk >> 2;
    int t8 = rest & 7, s = rest >> 3;
    int rt = t8 & 1, ct = t8 >> 1;
    const float* Ab = Pc + (size_t)s * 65536;
    gemm64(As, Bs, Ab, anp, PSTR, Ab, anp, PSTR, 256, 256,
           rt * 128, ct * 64, slice * 64,
           Pn + (size_t)slice * PSTR + (size_t)s * 65536, 256, 0, 256);
  } else {
    int e = blk - nSq;
    int slice = e & 3, rt = (e >> 2) & 1, rest2 = e >> 3;
    int ct = rest2 % ntct, s = rest2 / ntct;
    gemm64(As, Bs, Pc + (size_t)s * 65536, anp, PSTR,
           Vp + (size_t)s * 262144, 4, VPSTR, 1024, m,
           rt * 128, ct * 64, slice * 64,
           Vp + (size_t)slice * VPSTR + (size_t)s * 262144, 1024, m, m);
  }
}

// collapse 4 V planes -> dense V
__global__ __launch_bounds__(256) void k_reduceV(const float* __restrict__ Vp,
                                                 float* __restrict__ V) {
  int t = threadIdx.x;
  size_t base = (size_t)blockIdx.x * 1024;
  for (int e = 0; e < 4; ++e) {
    size_t idx = base + e * 256 + t;
    V[idx] = (Vp[idx] + Vp[VPSTR + idx]) + (Vp[2 * VPSTR + idx] + Vp[3 * VPSTR + idx]);
  }
}

// fused: ut row (s,k) -> twiddle -> in-LDS prefix scan -> atomic H contribution
__global__ __launch_bounds__(256) void k_utscan(const float* __restrict__ wt_re,
                                                const float* __restrict__ wt_im,
                                                const float* __restrict__ V,
                                                const float* __restrict__ w_mlp,
                                                float* __restrict__ H) {
  int blk = blockIdx.x;   // s*NM + k
  int s = blk / NM, k = blk & 31;
  int t = threadIdx.x;
  __shared__ float sr[LSEQ], si_[LSEQ];
  __shared__ float cr[256], ci[256];
  const float* wr = wt_re + (size_t)blk * NH;
  const float* wi_ = wt_im + (size_t)blk * NH;
  const float* Vs = V + (size_t)s * NH * LSEQ;
  float ar[4] = {0.f, 0.f, 0.f, 0.f}, ai[4] = {0.f, 0.f, 0.f, 0.f};
  for (int i = 0; i < NH; ++i) {
    float a = wr[i], b = wi_[i];
    const float* vrow = Vs + (size_t)i * LSEQ + t;
    #pragma unroll
    for (int e = 0; e < 4; ++e) {
      float v = vrow[256 * e];
      ar[e] += a * v; ai[e] += b * v;
    }
  }
  for (int e = 0; e < 4; ++e) {
    int d = t + 256 * e;
    int frac = (k * d) & 1023;
    float ang = -(TWO_PI / 1024.0f) * (float)frac;
    float sn, csn; sincosf(ang, &sn, &csn);
    sr[d] = ar[e] * csn - ai[e] * sn;
    si_[d] = ar[e] * sn + ai[e] * csn;
  }
  __syncthreads();
  float lr[4], li[4], rr = 0.f, ii = 0.f;
  for (int e = 0; e < 4; ++e) {
    rr += sr[4 * t + e]; ii += si_[4 * t + e];
    lr[e] = rr; li[e] = ii;
  }
  cr[t] = rr; ci[t] = ii;
  __syncthreads();
  for (int off = 1; off < 256; off <<= 1) {
    float pr = 0.f, pi = 0.f;
    if (t >= off) { pr = cr[t - off]; pi = ci[t - off]; }
    __syncthreads();
    cr[t] += pr; ci[t] += pi;
    __syncthreads();
  }
  float offr = (t > 0) ? cr[t - 1] : 0.0f;
  float offi = (t > 0) ? ci[t - 1] : 0.0f;
  for (int e = 0; e < 4; ++e) {
    sr[4 * t + e] = lr[e] + offr;
    si_[4 * t + e] = li[e] + offi;
  }
  __syncthreads();
  float wm = w_mlp[s];
  float coef = wm * ((k == 0) ? 1.0f : 2.0f) * (1.0f / LSEQ);
  for (int e = 0; e < 4; ++e) {
    int tau = t + 256 * e;
    int mIdx = 1023 - tau;
    int frac = (k * (tau + 1)) & 1023;
    float ang = -(TWO_PI / 1024.0f) * (float)frac;
    float sn, csn; sincosf(ang, &sn, &csn);
    float val = coef * (sr[mIdx] * csn - si_[mIdx] * sn);
    atomicAdd(&H[tau], val);
  }
}

// feat per (b,c) + atomic accumulate into out (pre-initialized to b_fc)
__global__ __launch_bounds__(256) void k_feat(const float* __restrict__ x,
                                              const float* __restrict__ means,
                                              const float* __restrict__ stdev,
                                              const float* __restrict__ aw,
                                              const float* __restrict__ ab,
                                              const float* __restrict__ b_mlp,
                                              const float* __restrict__ H,
                                              const float* __restrict__ w_fc,
                                              float* __restrict__ out) {
  int bc = blockIdx.x; int b = bc / NC, c = bc % NC;
  __shared__ float red[256];
  int t = threadIdx.x;
  float mn = means[bc], sd = stdev[bc];
  float w = aw[c], bb = ab[c];
  float acc = 0.f;
  for (int e = 0; e < 4; ++e) {
    int tau = t + 256 * e;
    float xv = x[((size_t)b * LSEQ + tau) * NC + c];
    float f = (xv - mn) / sd * w + bb;
    acc += f * H[tau];
  }
  float sum = block_reduce_sum(acc, red);
  if (t == 0) {
    float mr = sum + b_mlp[0];
    float featv = (mr - bb) / (w + 1e-10f) * sd + mn;
    #pragma unroll
    for (int d = 0; d < 5; ++d)
      atomicAdd(&out[b * 5 + d], featv * w_fc[d * NC + c]);
  }
}

extern "C" void kernel_launch(void* const* d_in, const int* in_sizes, int n_in,
                              void* d_out, int out_size, void* d_ws, size_t ws_size,
                              hipStream_t stream) {
  const float* x_enc   = (const float*)d_in[0];
  const float* aw      = (const float*)d_in[1];
  const float* ab      = (const float*)d_in[2];
  const float* wre     = (const float*)d_in[3];
  const float* wim     = (const float*)d_in[4];
  const float* w_mlp   = (const float*)d_in[5];
  const float* b_mlp   = (const float*)d_in[6];
  const float* w_fc    = (const float*)d_in[7];
  const float* b_fc    = (const float*)d_in[8];
  const float* A_mats  = (const float*)d_in[9];
  const float* B_vecs  = (const float*)d_in[10];
  const float* ev      = (const float*)d_in[11];

  float* ws    = (float*)d_ws;
  float* means = ws + OFF_MEANS;
  float* stdev = ws + OFF_STDEV;
  float* epart = ws + OFF_EPART;
  float* wt_re = ws + OFF_WT_RE;
  float* wt_im = ws + OFF_WT_IM;
  float* Vp    = ws + OFF_VP;
  float* V     = ws + OFF_V;
  float* PP0   = ws + OFF_PP0;
  float* PP1   = ws + OFF_PP1;
  float* H     = ws + OFF_H;
  float* out   = (float*)d_out;

  k_front<<<290, 256, 0, stream>>>(x_enc, B_vecs, ev, b_fc, means, stdev, epart, Vp, H, out);
  k_wtilde<<<NS * NH, 256, 0, stream>>>(wre, wim, epart, wt_re, wt_im);

  const float* Pc = A_mats; int anp = 1;
  float* Pn = PP0;
  for (int si = 0; si < 10; ++si) {
    int m = 1 << si;
    int doSq = (si < 9);
    int nSq = doSq ? 96 : 0;
    int ntct = (m + 63) >> 6;
    int grid = nSq + 24 * ntct;
    k_chain<<<grid, 256, 0, stream>>>(Pc, Pn, Vp, m, anp, nSq, ntct);
    if (doSq) { Pc = Pn; anp = 4; Pn = (Pn == PP0) ? PP1 : PP0; }
  }

  k_reduceV<<<768, 256, 0, stream>>>(Vp, V);
  k_utscan<<<NS * NM, 256, 0, stream>>>(wt_re, wt_im, V, w_mlp, H);
  k_feat<<<192, 256, 0, stream>>>(x_enc, means, stdev, aw, ab, b_mlp, H, w_fc, out);
}

// Round 8
// 179.383 us; speedup vs baseline: 3.2176x; 3.2176x over previous
//
#include <hip/hip_runtime.h>
#include <math.h>

#define LSEQ 1024
#define NB 16
#define NC 12
#define NH 256
#define NM 32
#define NS 3
#define TWO_PI 6.283185307179586f

#define PSTR  196608     // P plane stride (3*256*256)
#define VPSTR 786432     // V plane stride (3*256*1024)

// ---- workspace layout (float offsets) ----
#define OFF_MEANS 0            // 192
#define OFF_STDEV 192          // 192
#define OFF_EPART 384          // 24576
#define OFF_WT_RE 24960        // 24576
#define OFF_WT_IM 49536        // 24576
#define OFF_VP    74112        // 4 planes x 786432 = 3145728
#define OFF_V     3219840      // 786432 (dense)
#define OFF_PP0   4006272      // 786432 (4 planes x 196608)
#define OFF_PP1   4792704      // 786432
#define OFF_H     5579136      // 1024

__device__ __forceinline__ float block_reduce_sum(float v, float* sbuf) {
  int t = threadIdx.x;
  sbuf[t] = v; __syncthreads();
  for (int off = 128; off > 0; off >>= 1) {
    if (t < off) sbuf[t] += sbuf[t + off];
    __syncthreads();
  }
  float r = sbuf[0];
  __syncthreads();
  return r;
}

// front: stats (0..191) | epart (192..287) | Vp col0 init (288) | H/out init (289)
__global__ __launch_bounds__(256) void k_front(const float* __restrict__ x,
                                               const float* __restrict__ Bv,
                                               const float* __restrict__ ev,
                                               const float* __restrict__ b_fc,
                                               float* __restrict__ means,
                                               float* __restrict__ stdev,
                                               float* __restrict__ epart,
                                               float* __restrict__ Vp,
                                               float* __restrict__ H,
                                               float* __restrict__ out) {
  __shared__ float smem[1280];
  int blk = blockIdx.x;
  int t = threadIdx.x;
  if (blk < 192) {
    int b = blk / NC, c = blk % NC;
    float* xs = smem;
    float* red = smem + 1024;
    for (int e = 0; e < 4; ++e) {
      int tau = t + 256 * e;
      xs[tau] = x[((size_t)b * LSEQ + tau) * NC + c];
    }
    __syncthreads();
    float p = 0.f;
    for (int e = 0; e < 4; ++e) p += xs[t + 256 * e];
    float sum = block_reduce_sum(p, red);
    float mean = sum * (1.0f / LSEQ);
    float q = 0.f;
    for (int e = 0; e < 4; ++e) { float d = xs[t + 256 * e] - mean; q += d * d; }
    float sq = block_reduce_sum(q, red);
    if (t == 0) {
      means[blk] = mean;
      stdev[blk] = sqrtf(sq * (1.0f / LSEQ) + 1e-5f);
    }
  } else if (blk < 288) {
    int bb = blk - 192;          // s*32 + chunk
    int s = bb >> 5, ch = bb & 31;
    float acc = 0.f;
    const float* base = ev + (size_t)s * LSEQ * NH + (size_t)ch * 32 * NH + t;
    for (int l = 0; l < 32; ++l) acc += base[(size_t)l * NH];
    epart[(size_t)bb * NH + t] = acc;
  } else if (blk == 288) {
    // col 0 of each plane: plane0 = B, planes 1-3 = 0
    for (int pl = 0; pl < 4; ++pl)
      for (int row = t; row < 768; row += 256)
        Vp[(size_t)pl * VPSTR + (size_t)row * LSEQ] = (pl == 0) ? Bv[row] : 0.0f;
  } else {
    for (int e = 0; e < 4; ++e) H[t + 256 * e] = 0.0f;
    if (t < NB * 5) out[t] = b_fc[t % 5];
  }
}

// standalone wtilde: 768 blocks, one (s,i) each; float4 streaming of w_spec.
__global__ __launch_bounds__(256) void k_wtilde(const float* __restrict__ wre,
                                                const float* __restrict__ wim,
                                                const float* __restrict__ epart,
                                                float* __restrict__ wt_re,
                                                float* __restrict__ wt_im) {
  int blk = blockIdx.x; int s = blk / NH, i = blk % NH;
  int t = threadIdx.x;
  __shared__ float ebs[NH];
  __shared__ float sr[1024], si2[1024];
  float eb = 0.f;
  for (int ch = 0; ch < 32; ++ch) eb += epart[(s * 32 + ch) * 256 + t];
  ebs[t] = eb * (1.0f / LSEQ);
  __syncthreads();
  const float* br = wre + (size_t)(s * NH + i) * NH * NM;
  const float* bi = wim + (size_t)(s * NH + i) * NH * NM;
  float aR[4] = {0.f, 0.f, 0.f, 0.f}, aI[4] = {0.f, 0.f, 0.f, 0.f};
  #pragma unroll
  for (int it = 0; it < 8; ++it) {
    int o = (t >> 3) + 32 * it;
    float e = ebs[o];
    float4 vr = *(const float4*)(br + (size_t)t * 4 + 1024 * it);
    float4 vi = *(const float4*)(bi + (size_t)t * 4 + 1024 * it);
    aR[0] += e * vr.x; aR[1] += e * vr.y; aR[2] += e * vr.z; aR[3] += e * vr.w;
    aI[0] += e * vi.x; aI[1] += e * vi.y; aI[2] += e * vi.z; aI[3] += e * vi.w;
  }
  *(float4*)(sr + t * 4)  = make_float4(aR[0], aR[1], aR[2], aR[3]);
  *(float4*)(si2 + t * 4) = make_float4(aI[0], aI[1], aI[2], aI[3]);
  __syncthreads();
  if (t < 32) {
    float r = 0.f, im = 0.f;
    #pragma unroll
    for (int og = 0; og < 32; ++og) { r += sr[og * 32 + t]; im += si2[og * 32 + t]; }
    wt_re[(size_t)(s * NM + t) * NH + i] = r;
    wt_im[(size_t)(s * NM + t) * NH + i] = im;
  }
}

#define FMA_ROW(r, av) { acc[r][0] += (av)*b4.x; acc[r][1] += (av)*b4.y; acc[r][2] += (av)*b4.z; acc[r][3] += (av)*b4.w; }

// 128x64 output tile, K-slice of 64 (2 chunks of 32). 256 threads, 8x4 acc/thread.
// Plane counts are COMPILE-TIME so the sum loops fully unroll into independent loads.
template<int ANP, int BNP>
__device__ __forceinline__ void gemm64(float* As, float* Bs,
                       const float* Abase, int apstr,
                       const float* Bbase, int bpstr, int bld, int colLimit,
                       int rowbase, int colbase, int kb0,
                       float* outp, int outld, int outcol0, int outColLim) {
  const int tid = threadIdx.x;
  const int tx = tid & 15, ty = tid >> 4;
  const int kkA = tid & 31, rA = tid >> 5;
  const int jB = tid & 63, kB = tid >> 6;
  float acc[8][4];
  #pragma unroll
  for (int i = 0; i < 8; ++i)
    #pragma unroll
    for (int j = 0; j < 4; ++j) acc[i][j] = 0.f;

  for (int ch = 0; ch < 2; ++ch) {
    int kb = kb0 + ch * 32;
    #pragma unroll
    for (int p = 0; p < 16; ++p) {
      int row = rowbase + rA + 8 * p;
      float pv[ANP];
      #pragma unroll
      for (int pp = 0; pp < ANP; ++pp)
        pv[pp] = Abase[(size_t)pp * apstr + (size_t)row * 256 + kb + kkA];
      float v = pv[0];
      #pragma unroll
      for (int pp = 1; pp < ANP; ++pp) v += pv[pp];
      As[kkA * 132 + rA + 8 * p] = v;
    }
    #pragma unroll
    for (int q = 0; q < 8; ++q) {
      int kk = kB + 4 * q;
      int j = colbase + jB;
      float v = 0.f;
      if (j < colLimit) {
        float pv[BNP];
        #pragma unroll
        for (int pp = 0; pp < BNP; ++pp)
          pv[pp] = Bbase[(size_t)pp * bpstr + (size_t)(kb + kk) * bld + j];
        v = pv[0];
        #pragma unroll
        for (int pp = 1; pp < BNP; ++pp) v += pv[pp];
      }
      Bs[kk * 68 + jB] = v;
    }
    __syncthreads();
    #pragma unroll
    for (int kk = 0; kk < 32; ++kk) {
      float4 b4 = *(const float4*)(Bs + kk * 68 + tx * 4);
      float4 a0 = *(const float4*)(As + kk * 132 + ty * 8);
      float4 a1 = *(const float4*)(As + kk * 132 + ty * 8 + 4);
      FMA_ROW(0, a0.x) FMA_ROW(1, a0.y) FMA_ROW(2, a0.z) FMA_ROW(3, a0.w)
      FMA_ROW(4, a1.x) FMA_ROW(5, a1.y) FMA_ROW(6, a1.z) FMA_ROW(7, a1.w)
    }
    __syncthreads();
  }
  if (colbase + 64 <= outColLim) {
    #pragma unroll
    for (int i = 0; i < 8; ++i) {
      int row = rowbase + ty * 8 + i;
      float4 st; st.x = acc[i][0]; st.y = acc[i][1]; st.z = acc[i][2]; st.w = acc[i][3];
      *(float4*)(outp + (size_t)row * outld + outcol0 + colbase + tx * 4) = st;
    }
  } else {
    #pragma unroll
    for (int i = 0; i < 8; ++i) {
      int row = rowbase + ty * 8 + i;
      #pragma unroll
      for (int j = 0; j < 4; ++j) {
        int c = colbase + tx * 4 + j;
        if (c < outColLim) outp[(size_t)row * outld + outcol0 + c] = acc[i][j];
      }
    }
  }
}

// one chain stage: squares (split-K4 -> P planes) | extends (split-K4 -> V planes)
template<int ANP>
__global__ __launch_bounds__(256) void k_chain(const float* __restrict__ Pc,
                                               float* __restrict__ Pn,
                                               float* __restrict__ Vp,
                                               int m, int nSq, int ntct) {
  __shared__ float smem[6608];
  float* As = smem;            // [32][132]
  float* Bs = smem + 4224;     // [32][68]
  const int blk = blockIdx.x;
  if (blk < nSq) {
    int slice = blk & 3, rest = blk >> 2;
    int t8 = rest & 7, s = rest >> 3;
    int rt = t8 & 1, ct = t8 >> 1;
    const float* Ab = Pc + (size_t)s * 65536;
    gemm64<ANP, ANP>(As, Bs, Ab, PSTR, Ab, PSTR, 256, 256,
           rt * 128, ct * 64, slice * 64,
           Pn + (size_t)slice * PSTR + (size_t)s * 65536, 256, 0, 256);
  } else {
    int e = blk - nSq;
    int slice = e & 3, rt = (e >> 2) & 1, rest2 = e >> 3;
    int ct = rest2 % ntct, s = rest2 / ntct;
    gemm64<ANP, 4>(As, Bs, Pc + (size_t)s * 65536, PSTR,
           Vp + (size_t)s * 262144, VPSTR, 1024, m,
           rt * 128, ct * 64, slice * 64,
           Vp + (size_t)slice * VPSTR + (size_t)s * 262144, 1024, m, m);
  }
}

// collapse 4 V planes -> dense V
__global__ __launch_bounds__(256) void k_reduceV(const float* __restrict__ Vp,
                                                 float* __restrict__ V) {
  int t = threadIdx.x;
  size_t base = (size_t)blockIdx.x * 1024;
  for (int e = 0; e < 4; ++e) {
    size_t idx = base + e * 256 + t;
    V[idx] = (Vp[idx] + Vp[VPSTR + idx]) + (Vp[2 * VPSTR + idx] + Vp[3 * VPSTR + idx]);
  }
}

// fused: ut row (s,k) -> twiddle -> in-LDS prefix scan -> atomic H contribution
__global__ __launch_bounds__(256) void k_utscan(const float* __restrict__ wt_re,
                                                const float* __restrict__ wt_im,
                                                const float* __restrict__ V,
                                                const float* __restrict__ w_mlp,
                                                float* __restrict__ H) {
  int blk = blockIdx.x;   // s*NM + k
  int s = blk / NM, k = blk & 31;
  int t = threadIdx.x;
  __shared__ float sr[LSEQ], si_[LSEQ];
  __shared__ float cr[256], ci[256];
  const float* wr = wt_re + (size_t)blk * NH;
  const float* wi_ = wt_im + (size_t)blk * NH;
  const float* Vs = V + (size_t)s * NH * LSEQ;
  float ar[4] = {0.f, 0.f, 0.f, 0.f}, ai[4] = {0.f, 0.f, 0.f, 0.f};
  for (int i = 0; i < NH; ++i) {
    float a = wr[i], b = wi_[i];
    const float* vrow = Vs + (size_t)i * LSEQ + t;
    #pragma unroll
    for (int e = 0; e < 4; ++e) {
      float v = vrow[256 * e];
      ar[e] += a * v; ai[e] += b * v;
    }
  }
  for (int e = 0; e < 4; ++e) {
    int d = t + 256 * e;
    int frac = (k * d) & 1023;
    float ang = -(TWO_PI / 1024.0f) * (float)frac;
    float sn, csn; sincosf(ang, &sn, &csn);
    sr[d] = ar[e] * csn - ai[e] * sn;
    si_[d] = ar[e] * sn + ai[e] * csn;
  }
  __syncthreads();
  float lr[4], li[4], rr = 0.f, ii = 0.f;
  for (int e = 0; e < 4; ++e) {
    rr += sr[4 * t + e]; ii += si_[4 * t + e];
    lr[e] = rr; li[e] = ii;
  }
  cr[t] = rr; ci[t] = ii;
  __syncthreads();
  for (int off = 1; off < 256; off <<= 1) {
    float pr = 0.f, pi = 0.f;
    if (t >= off) { pr = cr[t - off]; pi = ci[t - off]; }
    __syncthreads();
    cr[t] += pr; ci[t] += pi;
    __syncthreads();
  }
  float offr = (t > 0) ? cr[t - 1] : 0.0f;
  float offi = (t > 0) ? ci[t - 1] : 0.0f;
  for (int e = 0; e < 4; ++e) {
    sr[4 * t + e] = lr[e] + offr;
    si_[4 * t + e] = li[e] + offi;
  }
  __syncthreads();
  float wm = w_mlp[s];
  float coef = wm * ((k == 0) ? 1.0f : 2.0f) * (1.0f / LSEQ);
  for (int e = 0; e < 4; ++e) {
    int tau = t + 256 * e;
    int mIdx = 1023 - tau;
    int frac = (k * (tau + 1)) & 1023;
    float ang = -(TWO_PI / 1024.0f) * (float)frac;
    float sn, csn; sincosf(ang, &sn, &csn);
    float val = coef * (sr[mIdx] * csn - si_[mIdx] * sn);
    atomicAdd(&H[tau], val);
  }
}

// feat per (b,c) + atomic accumulate into out (pre-initialized to b_fc)
__global__ __launch_bounds__(256) void k_feat(const float* __restrict__ x,
                                              const float* __restrict__ means,
                                              const float* __restrict__ stdev,
                                              const float* __restrict__ aw,
                                              const float* __restrict__ ab,
                                              const float* __restrict__ b_mlp,
                                              const float* __restrict__ H,
                                              const float* __restrict__ w_fc,
                                              float* __restrict__ out) {
  int bc = blockIdx.x; int b = bc / NC, c = bc % NC;
  __shared__ float red[256];
  int t = threadIdx.x;
  float mn = means[bc], sd = stdev[bc];
  float w = aw[c], bb = ab[c];
  float acc = 0.f;
  for (int e = 0; e < 4; ++e) {
    int tau = t + 256 * e;
    float xv = x[((size_t)b * LSEQ + tau) * NC + c];
    float f = (xv - mn) / sd * w + bb;
    acc += f * H[tau];
  }
  float sum = block_reduce_sum(acc, red);
  if (t == 0) {
    float mr = sum + b_mlp[0];
    float featv = (mr - bb) / (w + 1e-10f) * sd + mn;
    #pragma unroll
    for (int d = 0; d < 5; ++d)
      atomicAdd(&out[b * 5 + d], featv * w_fc[d * NC + c]);
  }
}

extern "C" void kernel_launch(void* const* d_in, const int* in_sizes, int n_in,
                              void* d_out, int out_size, void* d_ws, size_t ws_size,
                              hipStream_t stream) {
  const float* x_enc   = (const float*)d_in[0];
  const float* aw      = (const float*)d_in[1];
  const float* ab      = (const float*)d_in[2];
  const float* wre     = (const float*)d_in[3];
  const float* wim     = (const float*)d_in[4];
  const float* w_mlp   = (const float*)d_in[5];
  const float* b_mlp   = (const float*)d_in[6];
  const float* w_fc    = (const float*)d_in[7];
  const float* b_fc    = (const float*)d_in[8];
  const float* A_mats  = (const float*)d_in[9];
  const float* B_vecs  = (const float*)d_in[10];
  const float* ev      = (const float*)d_in[11];

  float* ws    = (float*)d_ws;
  float* means = ws + OFF_MEANS;
  float* stdev = ws + OFF_STDEV;
  float* epart = ws + OFF_EPART;
  float* wt_re = ws + OFF_WT_RE;
  float* wt_im = ws + OFF_WT_IM;
  float* Vp    = ws + OFF_VP;
  float* V     = ws + OFF_V;
  float* PP0   = ws + OFF_PP0;
  float* PP1   = ws + OFF_PP1;
  float* H     = ws + OFF_H;
  float* out   = (float*)d_out;

  k_front<<<290, 256, 0, stream>>>(x_enc, B_vecs, ev, b_fc, means, stdev, epart, Vp, H, out);
  k_wtilde<<<NS * NH, 256, 0, stream>>>(wre, wim, epart, wt_re, wt_im);

  const float* Pc = A_mats;
  float* Pn = PP0;
  for (int si = 0; si < 10; ++si) {
    int m = 1 << si;
    int doSq = (si < 9);
    int nSq = doSq ? 96 : 0;
    int ntct = (m + 63) >> 6;
    int grid = nSq + 24 * ntct;
    if (si == 0)
      k_chain<1><<<grid, 256, 0, stream>>>(Pc, Pn, Vp, m, nSq, ntct);
    else
      k_chain<4><<<grid, 256, 0, stream>>>(Pc, Pn, Vp, m, nSq, ntct);
    if (doSq) { Pc = Pn; Pn = (Pn == PP0) ? PP1 : PP0; }
  }

  k_reduceV<<<768, 256, 0, stream>>>(Vp, V);
  k_utscan<<<NS * NM, 256, 0, stream>>>(wt_re, wt_im, V, w_mlp, H);
  k_feat<<<192, 256, 0, stream>>>(x_enc, means, stdev, aw, ab, b_mlp, H, w_fc, out);
}

// Round 9
// 173.745 us; speedup vs baseline: 3.3220x; 1.0325x over previous
//
#include <hip/hip_runtime.h>
#include <math.h>

#define LSEQ 1024
#define NB 16
#define NC 12
#define NH 256
#define NM 32
#define NS 3
#define TWO_PI 6.283185307179586f

#define PSTR  196608     // P plane stride (3*256*256)
#define VPSTR 786432     // V plane stride (3*256*1024)

// ---- workspace layout (float offsets) ----
#define OFF_MEANS 0            // 192
#define OFF_STDEV 192          // 192
#define OFF_EPART 384          // 24576
#define OFF_WT_RE 24960        // 24576
#define OFF_WT_IM 49536        // 24576
#define OFF_VP    74112        // 4 planes x 786432 = 3145728
#define OFF_V     3219840      // 786432 (dense)
#define OFF_PP0   4006272      // 786432 (4 planes x 196608)
#define OFF_PP1   4792704      // 786432
#define OFF_H     5579136      // 1024

__device__ __forceinline__ float block_reduce_sum(float v, float* sbuf) {
  int t = threadIdx.x;
  sbuf[t] = v; __syncthreads();
  for (int off = 128; off > 0; off >>= 1) {
    if (t < off) sbuf[t] += sbuf[t + off];
    __syncthreads();
  }
  float r = sbuf[0];
  __syncthreads();
  return r;
}

// front: epart (0..95) | Vp col0 init (96) | H/out init (97)
__global__ __launch_bounds__(256) void k_front(const float* __restrict__ Bv,
                                               const float* __restrict__ ev,
                                               const float* __restrict__ b_fc,
                                               float* __restrict__ epart,
                                               float* __restrict__ Vp,
                                               float* __restrict__ H,
                                               float* __restrict__ out) {
  int blk = blockIdx.x;
  int t = threadIdx.x;
  if (blk < 96) {
    int s = blk >> 5, ch = blk & 31;
    float acc = 0.f;
    const float* base = ev + (size_t)s * LSEQ * NH + (size_t)ch * 32 * NH + t;
    for (int l = 0; l < 32; ++l) acc += base[(size_t)l * NH];
    epart[(size_t)blk * NH + t] = acc;
  } else if (blk == 96) {
    for (int pl = 0; pl < 4; ++pl)
      for (int row = t; row < 768; row += 256)
        Vp[(size_t)pl * VPSTR + (size_t)row * LSEQ] = (pl == 0) ? Bv[row] : 0.0f;
  } else {
    for (int e = 0; e < 4; ++e) H[t + 256 * e] = 0.0f;
    if (t < NB * 5) out[t] = b_fc[t % 5];
  }
}

// float4 wtilde task for one (s,i): wt[s,k,i] = sum_o ebar[s,o]*w[s,i,o,k]
__device__ __forceinline__ void wtilde_task(int w, float* smem,
                                            const float* __restrict__ wre,
                                            const float* __restrict__ wim,
                                            const float* __restrict__ epart,
                                            float* __restrict__ wt_re,
                                            float* __restrict__ wt_im) {
  int s = w >> 8, i = w & 255;
  int t = threadIdx.x;
  float* ebs = smem;
  float* sr  = smem + 256;
  float* si2 = smem + 1280;
  float eb = 0.f;
  for (int ch = 0; ch < 32; ++ch) eb += epart[(s * 32 + ch) * 256 + t];
  ebs[t] = eb * (1.0f / LSEQ);
  __syncthreads();
  const float* br = wre + (size_t)(s * NH + i) * NH * NM;
  const float* bi = wim + (size_t)(s * NH + i) * NH * NM;
  float aR[4] = {0.f, 0.f, 0.f, 0.f}, aI[4] = {0.f, 0.f, 0.f, 0.f};
  #pragma unroll
  for (int it = 0; it < 8; ++it) {
    int o = (t >> 3) + 32 * it;
    float e = ebs[o];
    float4 vr = *(const float4*)(br + (size_t)t * 4 + 1024 * it);
    float4 vi = *(const float4*)(bi + (size_t)t * 4 + 1024 * it);
    aR[0] += e * vr.x; aR[1] += e * vr.y; aR[2] += e * vr.z; aR[3] += e * vr.w;
    aI[0] += e * vi.x; aI[1] += e * vi.y; aI[2] += e * vi.z; aI[3] += e * vi.w;
  }
  *(float4*)(sr + t * 4)  = make_float4(aR[0], aR[1], aR[2], aR[3]);
  *(float4*)(si2 + t * 4) = make_float4(aI[0], aI[1], aI[2], aI[3]);
  __syncthreads();
  if (t < 32) {
    float r = 0.f, im = 0.f;
    #pragma unroll
    for (int og = 0; og < 32; ++og) { r += sr[og * 32 + t]; im += si2[og * 32 + t]; }
    wt_re[(size_t)(s * NM + t) * NH + i] = r;
    wt_im[(size_t)(s * NM + t) * NH + i] = im;
  }
}

#define FMA_ROW(r, av) { acc[r][0] += (av)*b4.x; acc[r][1] += (av)*b4.y; acc[r][2] += (av)*b4.z; acc[r][3] += (av)*b4.w; }

// 128x64 output tile, K-slice of 64 (2 chunks of 32). Plane counts compile-time.
template<int ANP, int BNP>
__device__ __forceinline__ void gemm64(float* As, float* Bs,
                       const float* Abase, int apstr,
                       const float* Bbase, int bpstr, int bld, int colLimit,
                       int rowbase, int colbase, int kb0,
                       float* outp, int outld, int outcol0, int outColLim) {
  const int tid = threadIdx.x;
  const int tx = tid & 15, ty = tid >> 4;
  const int kkA = tid & 31, rA = tid >> 5;
  const int jB = tid & 63, kB = tid >> 6;
  float acc[8][4];
  #pragma unroll
  for (int i = 0; i < 8; ++i)
    #pragma unroll
    for (int j = 0; j < 4; ++j) acc[i][j] = 0.f;

  for (int ch = 0; ch < 2; ++ch) {
    int kb = kb0 + ch * 32;
    #pragma unroll
    for (int p = 0; p < 16; ++p) {
      int row = rowbase + rA + 8 * p;
      float pv[ANP];
      #pragma unroll
      for (int pp = 0; pp < ANP; ++pp)
        pv[pp] = Abase[(size_t)pp * apstr + (size_t)row * 256 + kb + kkA];
      float v = pv[0];
      #pragma unroll
      for (int pp = 1; pp < ANP; ++pp) v += pv[pp];
      As[kkA * 132 + rA + 8 * p] = v;
    }
    #pragma unroll
    for (int q = 0; q < 8; ++q) {
      int kk = kB + 4 * q;
      int j = colbase + jB;
      float v = 0.f;
      if (j < colLimit) {
        float pv[BNP];
        #pragma unroll
        for (int pp = 0; pp < BNP; ++pp)
          pv[pp] = Bbase[(size_t)pp * bpstr + (size_t)(kb + kk) * bld + j];
        v = pv[0];
        #pragma unroll
        for (int pp = 1; pp < BNP; ++pp) v += pv[pp];
      }
      Bs[kk * 68 + jB] = v;
    }
    __syncthreads();
    #pragma unroll
    for (int kk = 0; kk < 32; ++kk) {
      float4 b4 = *(const float4*)(Bs + kk * 68 + tx * 4);
      float4 a0 = *(const float4*)(As + kk * 132 + ty * 8);
      float4 a1 = *(const float4*)(As + kk * 132 + ty * 8 + 4);
      FMA_ROW(0, a0.x) FMA_ROW(1, a0.y) FMA_ROW(2, a0.z) FMA_ROW(3, a0.w)
      FMA_ROW(4, a1.x) FMA_ROW(5, a1.y) FMA_ROW(6, a1.z) FMA_ROW(7, a1.w)
    }
    __syncthreads();
  }
  if (colbase + 64 <= outColLim) {
    #pragma unroll
    for (int i = 0; i < 8; ++i) {
      int row = rowbase + ty * 8 + i;
      float4 st; st.x = acc[i][0]; st.y = acc[i][1]; st.z = acc[i][2]; st.w = acc[i][3];
      *(float4*)(outp + (size_t)row * outld + outcol0 + colbase + tx * 4) = st;
    }
  } else {
    #pragma unroll
    for (int i = 0; i < 8; ++i) {
      int row = rowbase + ty * 8 + i;
      #pragma unroll
      for (int j = 0; j < 4; ++j) {
        int c = colbase + tx * 4 + j;
        if (c < outColLim) outp[(size_t)row * outld + outcol0 + c] = acc[i][j];
      }
    }
  }
}

// chain stage: squares | extends | wtilde filler | stats filler | reduceV-half filler
template<int ANP>
__global__ __launch_bounds__(256) void k_chain(const float* __restrict__ Pc,
                                               float* __restrict__ Pn,
                                               float* __restrict__ Vp,
                                               int m, int nSq, int ntct,
                                               const float* __restrict__ wre,
                                               const float* __restrict__ wim,
                                               const float* __restrict__ epart,
                                               float* __restrict__ wt_re,
                                               float* __restrict__ wt_im,
                                               int wstart, int wcount,
                                               const float* __restrict__ x,
                                               float* __restrict__ means,
                                               float* __restrict__ stdev,
                                               int statCount, int redCount,
                                               float* __restrict__ V) {
  __shared__ float smem[6608];
  float* As = smem;            // [32][132]
  float* Bs = smem + 4224;     // [32][68]
  const int blk = blockIdx.x;
  const int t = threadIdx.x;
  const int nExt = 24 * ntct;
  const int b0 = nSq + nExt;
  if (blk < nSq) {
    int slice = blk & 3, rest = blk >> 2;
    int t8 = rest & 7, s = rest >> 3;
    int rt = t8 & 1, ct = t8 >> 1;
    const float* Ab = Pc + (size_t)s * 65536;
    gemm64<ANP, ANP>(As, Bs, Ab, PSTR, Ab, PSTR, 256, 256,
           rt * 128, ct * 64, slice * 64,
           Pn + (size_t)slice * PSTR + (size_t)s * 65536, 256, 0, 256);
  } else if (blk < b0) {
    int e = blk - nSq;
    int slice = e & 3, rt = (e >> 2) & 1, rest2 = e >> 3;
    int ct = rest2 % ntct, s = rest2 / ntct;
    gemm64<ANP, 4>(As, Bs, Pc + (size_t)s * 65536, PSTR,
           Vp + (size_t)s * 262144, VPSTR, 1024, m,
           rt * 128, ct * 64, slice * 64,
           Vp + (size_t)slice * VPSTR + (size_t)s * 262144, 1024, m, m);
  } else if (blk < b0 + wcount) {
    wtilde_task(wstart + (blk - b0), smem, wre, wim, epart, wt_re, wt_im);
  } else if (blk < b0 + wcount + statCount) {
    int bc = blk - b0 - wcount;
    int b = bc / NC, c = bc % NC;
    float* xs = smem;
    float* red = smem + 1024;
    for (int e = 0; e < 4; ++e) {
      int tau = t + 256 * e;
      xs[tau] = x[((size_t)b * LSEQ + tau) * NC + c];
    }
    __syncthreads();
    float p = 0.f;
    for (int e = 0; e < 4; ++e) p += xs[t + 256 * e];
    float sum = block_reduce_sum(p, red);
    float mean = sum * (1.0f / LSEQ);
    float q = 0.f;
    for (int e = 0; e < 4; ++e) { float d = xs[t + 256 * e] - mean; q += d * d; }
    float sq = block_reduce_sum(q, red);
    if (t == 0) {
      means[bc] = mean;
      stdev[bc] = sqrtf(sq * (1.0f / LSEQ) + 1e-5f);
    }
  } else if (blk < b0 + wcount + statCount + redCount) {
    int rid = blk - b0 - wcount - statCount;   // row 0..767; cols 0..511 (final after stage 8)
    for (int e = 0; e < 2; ++e) {
      size_t idx = (size_t)rid * 1024 + e * 256 + t;
      V[idx] = (Vp[idx] + Vp[VPSTR + idx]) + (Vp[2 * VPSTR + idx] + Vp[3 * VPSTR + idx]);
    }
  }
}

// collapse planes for cols 512..1023 (written by stage 9)
__global__ __launch_bounds__(256) void k_reduceV2(const float* __restrict__ Vp,
                                                  float* __restrict__ V) {
  int t = threadIdx.x;
  for (int e = 0; e < 2; ++e) {
    size_t idx = (size_t)blockIdx.x * 1024 + 512 + e * 256 + t;
    V[idx] = (Vp[idx] + Vp[VPSTR + idx]) + (Vp[2 * VPSTR + idx] + Vp[3 * VPSTR + idx]);
  }
}

// fused: ut row (s,k) -> twiddle -> in-LDS prefix scan -> atomic H contribution
__global__ __launch_bounds__(256) void k_utscan(const float* __restrict__ wt_re,
                                                const float* __restrict__ wt_im,
                                                const float* __restrict__ V,
                                                const float* __restrict__ w_mlp,
                                                float* __restrict__ H) {
  int blk = blockIdx.x;   // s*NM + k
  int s = blk / NM, k = blk & 31;
  int t = threadIdx.x;
  __shared__ float sr[LSEQ], si_[LSEQ];
  __shared__ float cr[256], ci[256];
  const float* wr = wt_re + (size_t)blk * NH;
  const float* wi_ = wt_im + (size_t)blk * NH;
  const float* Vs = V + (size_t)s * NH * LSEQ;
  float ar[4] = {0.f, 0.f, 0.f, 0.f}, ai[4] = {0.f, 0.f, 0.f, 0.f};
  for (int i = 0; i < NH; ++i) {
    float a = wr[i], b = wi_[i];
    const float* vrow = Vs + (size_t)i * LSEQ + t;
    #pragma unroll
    for (int e = 0; e < 4; ++e) {
      float v = vrow[256 * e];
      ar[e] += a * v; ai[e] += b * v;
    }
  }
  for (int e = 0; e < 4; ++e) {
    int d = t + 256 * e;
    int frac = (k * d) & 1023;
    float ang = -(TWO_PI / 1024.0f) * (float)frac;
    float sn, csn; sincosf(ang, &sn, &csn);
    sr[d] = ar[e] * csn - ai[e] * sn;
    si_[d] = ar[e] * sn + ai[e] * csn;
  }
  __syncthreads();
  float lr[4], li[4], rr = 0.f, ii = 0.f;
  for (int e = 0; e < 4; ++e) {
    rr += sr[4 * t + e]; ii += si_[4 * t + e];
    lr[e] = rr; li[e] = ii;
  }
  cr[t] = rr; ci[t] = ii;
  __syncthreads();
  for (int off = 1; off < 256; off <<= 1) {
    float pr = 0.f, pi = 0.f;
    if (t >= off) { pr = cr[t - off]; pi = ci[t - off]; }
    __syncthreads();
    cr[t] += pr; ci[t] += pi;
    __syncthreads();
  }
  float offr = (t > 0) ? cr[t - 1] : 0.0f;
  float offi = (t > 0) ? ci[t - 1] : 0.0f;
  for (int e = 0; e < 4; ++e) {
    sr[4 * t + e] = lr[e] + offr;
    si_[4 * t + e] = li[e] + offi;
  }
  __syncthreads();
  float wm = w_mlp[s];
  float coef = wm * ((k == 0) ? 1.0f : 2.0f) * (1.0f / LSEQ);
  for (int e = 0; e < 4; ++e) {
    int tau = t + 256 * e;
    int mIdx = 1023 - tau;
    int frac = (k * (tau + 1)) & 1023;
    float ang = -(TWO_PI / 1024.0f) * (float)frac;
    float sn, csn; sincosf(ang, &sn, &csn);
    float val = coef * (sr[mIdx] * csn - si_[mIdx] * sn);
    atomicAdd(&H[tau], val);
  }
}

// feat per (b,c) + atomic accumulate into out (pre-initialized to b_fc)
__global__ __launch_bounds__(256) void k_feat(const float* __restrict__ x,
                                              const float* __restrict__ means,
                                              const float* __restrict__ stdev,
                                              const float* __restrict__ aw,
                                              const float* __restrict__ ab,
                                              const float* __restrict__ b_mlp,
                                              const float* __restrict__ H,
                                              const float* __restrict__ w_fc,
                                              float* __restrict__ out) {
  int bc = blockIdx.x; int b = bc / NC, c = bc % NC;
  __shared__ float red[256];
  int t = threadIdx.x;
  float mn = means[bc], sd = stdev[bc];
  float w = aw[c], bb = ab[c];
  float acc = 0.f;
  for (int e = 0; e < 4; ++e) {
    int tau = t + 256 * e;
    float xv = x[((size_t)b * LSEQ + tau) * NC + c];
    float f = (xv - mn) / sd * w + bb;
    acc += f * H[tau];
  }
  float sum = block_reduce_sum(acc, red);
  if (t == 0) {
    float mr = sum + b_mlp[0];
    float featv = (mr - bb) / (w + 1e-10f) * sd + mn;
    #pragma unroll
    for (int d = 0; d < 5; ++d)
      atomicAdd(&out[b * 5 + d], featv * w_fc[d * NC + c]);
  }
}

extern "C" void kernel_launch(void* const* d_in, const int* in_sizes, int n_in,
                              void* d_out, int out_size, void* d_ws, size_t ws_size,
                              hipStream_t stream) {
  const float* x_enc   = (const float*)d_in[0];
  const float* aw      = (const float*)d_in[1];
  const float* ab      = (const float*)d_in[2];
  const float* wre     = (const float*)d_in[3];
  const float* wim     = (const float*)d_in[4];
  const float* w_mlp   = (const float*)d_in[5];
  const float* b_mlp   = (const float*)d_in[6];
  const float* w_fc    = (const float*)d_in[7];
  const float* b_fc    = (const float*)d_in[8];
  const float* A_mats  = (const float*)d_in[9];
  const float* B_vecs  = (const float*)d_in[10];
  const float* ev      = (const float*)d_in[11];

  float* ws    = (float*)d_ws;
  float* means = ws + OFF_MEANS;
  float* stdev = ws + OFF_STDEV;
  float* epart = ws + OFF_EPART;
  float* wt_re = ws + OFF_WT_RE;
  float* wt_im = ws + OFF_WT_IM;
  float* Vp    = ws + OFF_VP;
  float* V     = ws + OFF_V;
  float* PP0   = ws + OFF_PP0;
  float* PP1   = ws + OFF_PP1;
  float* H     = ws + OFF_H;
  float* out   = (float*)d_out;

  k_front<<<98, 256, 0, stream>>>(B_vecs, ev, b_fc, epart, Vp, H, out);

  static const int wst[5] = {0, 154, 308, 462, 616};
  static const int wcn[5] = {154, 154, 154, 154, 152};
  const float* Pc = A_mats;
  float* Pn = PP0;
  for (int si = 0; si < 10; ++si) {
    int m = 1 << si;
    int doSq = (si < 9);
    int nSq = doSq ? 96 : 0;
    int ntct = (m + 63) >> 6;
    int wstart = (si < 5) ? wst[si] : 0;
    int wcount = (si < 5) ? wcn[si] : 0;
    int statCount = (si == 0) ? 192 : 0;
    int redCount = (si == 9) ? 768 : 0;
    int grid = nSq + 24 * ntct + wcount + statCount + redCount;
    if (si == 0)
      k_chain<1><<<grid, 256, 0, stream>>>(Pc, Pn, Vp, m, nSq, ntct,
          wre, wim, epart, wt_re, wt_im, wstart, wcount,
          x_enc, means, stdev, statCount, redCount, V);
    else
      k_chain<4><<<grid, 256, 0, stream>>>(Pc, Pn, Vp, m, nSq, ntct,
          wre, wim, epart, wt_re, wt_im, wstart, wcount,
          x_enc, means, stdev, statCount, redCount, V);
    if (doSq) { Pc = Pn; Pn = (Pn == PP0) ? PP1 : PP0; }
  }

  k_reduceV2<<<768, 256, 0, stream>>>(Vp, V);
  k_utscan<<<NS * NM, 256, 0, stream>>>(wt_re, wt_im, V, w_mlp, H);
  k_feat<<<192, 256, 0, stream>>>(x_enc, means, stdev, aw, ab, b_mlp, H, w_fc, out);
}

// Round 10
// 172.828 us; speedup vs baseline: 3.3396x; 1.0053x over previous
//
#include <hip/hip_runtime.h>
#include <math.h>

#define LSEQ 1024
#define NB 16
#define NC 12
#define NH 256
#define NM 32
#define NS 3
#define TWO_PI 6.283185307179586f

#define NPL   8          // split-K planes
#define PSTR  196608     // P plane stride (3*256*256)
#define VPSTR 786432     // V plane stride (3*256*1024)

// ---- workspace layout (float offsets) ----
#define OFF_MEANS 0            // 192
#define OFF_STDEV 192          // 192
#define OFF_EPART 384          // 24576
#define OFF_WT_RE 24960        // 24576
#define OFF_WT_IM 49536        // 24576
#define OFF_VP    74112        // 8 planes x 786432 = 6291456
#define OFF_V     6365568      // 786432 (dense)
#define OFF_PP0   7152000      // 8 planes x 196608 = 1572864
#define OFF_PP1   8724864      // 1572864
#define OFF_H     10297728     // 1024
// total ~10.3M floats = 41.2 MB

__device__ __forceinline__ float block_reduce_sum(float v, float* sbuf) {
  int t = threadIdx.x;
  sbuf[t] = v; __syncthreads();
  for (int off = 128; off > 0; off >>= 1) {
    if (t < off) sbuf[t] += sbuf[t + off];
    __syncthreads();
  }
  float r = sbuf[0];
  __syncthreads();
  return r;
}

// front: epart (0..95) | Vp col0 init (96) | H/out init (97)
__global__ __launch_bounds__(256) void k_front(const float* __restrict__ Bv,
                                               const float* __restrict__ ev,
                                               const float* __restrict__ b_fc,
                                               float* __restrict__ epart,
                                               float* __restrict__ Vp,
                                               float* __restrict__ H,
                                               float* __restrict__ out) {
  int blk = blockIdx.x;
  int t = threadIdx.x;
  if (blk < 96) {
    int s = blk >> 5, ch = blk & 31;
    float acc = 0.f;
    const float* base = ev + (size_t)s * LSEQ * NH + (size_t)ch * 32 * NH + t;
    for (int l = 0; l < 32; ++l) acc += base[(size_t)l * NH];
    epart[(size_t)blk * NH + t] = acc;
  } else if (blk == 96) {
    for (int pl = 0; pl < NPL; ++pl)
      for (int row = t; row < 768; row += 256)
        Vp[(size_t)pl * VPSTR + (size_t)row * LSEQ] = (pl == 0) ? Bv[row] : 0.0f;
  } else {
    for (int e = 0; e < 4; ++e) H[t + 256 * e] = 0.0f;
    if (t < NB * 5) out[t] = b_fc[t % 5];
  }
}

// float4 wtilde task for one (s,i): wt[s,k,i] = sum_o ebar[s,o]*w[s,i,o,k]
__device__ __forceinline__ void wtilde_task(int w, float* smem,
                                            const float* __restrict__ wre,
                                            const float* __restrict__ wim,
                                            const float* __restrict__ epart,
                                            float* __restrict__ wt_re,
                                            float* __restrict__ wt_im) {
  int s = w >> 8, i = w & 255;
  int t = threadIdx.x;
  float* ebs = smem;
  float* sr  = smem + 256;
  float* si2 = smem + 1280;
  float eb = 0.f;
  for (int ch = 0; ch < 32; ++ch) eb += epart[(s * 32 + ch) * 256 + t];
  ebs[t] = eb * (1.0f / LSEQ);
  __syncthreads();
  const float* br = wre + (size_t)(s * NH + i) * NH * NM;
  const float* bi = wim + (size_t)(s * NH + i) * NH * NM;
  float aR[4] = {0.f, 0.f, 0.f, 0.f}, aI[4] = {0.f, 0.f, 0.f, 0.f};
  #pragma unroll
  for (int it = 0; it < 8; ++it) {
    int o = (t >> 3) + 32 * it;
    float e = ebs[o];
    float4 vr = *(const float4*)(br + (size_t)t * 4 + 1024 * it);
    float4 vi = *(const float4*)(bi + (size_t)t * 4 + 1024 * it);
    aR[0] += e * vr.x; aR[1] += e * vr.y; aR[2] += e * vr.z; aR[3] += e * vr.w;
    aI[0] += e * vi.x; aI[1] += e * vi.y; aI[2] += e * vi.z; aI[3] += e * vi.w;
  }
  *(float4*)(sr + t * 4)  = make_float4(aR[0], aR[1], aR[2], aR[3]);
  *(float4*)(si2 + t * 4) = make_float4(aI[0], aI[1], aI[2], aI[3]);
  __syncthreads();
  if (t < 32) {
    float r = 0.f, im = 0.f;
    #pragma unroll
    for (int og = 0; og < 32; ++og) { r += sr[og * 32 + t]; im += si2[og * 32 + t]; }
    wt_re[(size_t)(s * NM + t) * NH + i] = r;
    wt_im[(size_t)(s * NM + t) * NH + i] = im;
  }
  __syncthreads();
}

#define FMA_ROW(r, av) { acc[r][0] += (av)*b4.x; acc[r][1] += (av)*b4.y; acc[r][2] += (av)*b4.z; acc[r][3] += (av)*b4.w; }

// 128x64 output tile, single K-slice of 32 (one barrier round). 8x4 acc/thread.
// Plane counts compile-time so sum loops fully unroll into pipelined loads.
template<int ANP, int BNP>
__device__ __forceinline__ void gemm32(float* As, float* Bs,
                       const float* Abase, int apstr,
                       const float* Bbase, int bpstr, int bld, int colLimit,
                       int rowbase, int colbase, int kb,
                       float* outp, int outld, int outcol0, int outColLim) {
  const int tid = threadIdx.x;
  const int tx = tid & 15, ty = tid >> 4;
  const int kkA = tid & 31, rA = tid >> 5;
  const int jB = tid & 63, kB = tid >> 6;
  float acc[8][4];
  #pragma unroll
  for (int i = 0; i < 8; ++i)
    #pragma unroll
    for (int j = 0; j < 4; ++j) acc[i][j] = 0.f;

  #pragma unroll
  for (int p = 0; p < 16; ++p) {
    int row = rowbase + rA + 8 * p;
    float pv[ANP];
    #pragma unroll
    for (int pp = 0; pp < ANP; ++pp)
      pv[pp] = Abase[(size_t)pp * apstr + (size_t)row * 256 + kb + kkA];
    float v = pv[0];
    #pragma unroll
    for (int pp = 1; pp < ANP; ++pp) v += pv[pp];
    As[kkA * 132 + rA + 8 * p] = v;
  }
  #pragma unroll
  for (int q = 0; q < 8; ++q) {
    int kk = kB + 4 * q;
    int j = colbase + jB;
    float v = 0.f;
    if (j < colLimit) {
      float pv[BNP];
      #pragma unroll
      for (int pp = 0; pp < BNP; ++pp)
        pv[pp] = Bbase[(size_t)pp * bpstr + (size_t)(kb + kk) * bld + j];
      v = pv[0];
      #pragma unroll
      for (int pp = 1; pp < BNP; ++pp) v += pv[pp];
    }
    Bs[kk * 68 + jB] = v;
  }
  __syncthreads();
  #pragma unroll
  for (int kk = 0; kk < 32; ++kk) {
    float4 b4 = *(const float4*)(Bs + kk * 68 + tx * 4);
    float4 a0 = *(const float4*)(As + kk * 132 + ty * 8);
    float4 a1 = *(const float4*)(As + kk * 132 + ty * 8 + 4);
    FMA_ROW(0, a0.x) FMA_ROW(1, a0.y) FMA_ROW(2, a0.z) FMA_ROW(3, a0.w)
    FMA_ROW(4, a1.x) FMA_ROW(5, a1.y) FMA_ROW(6, a1.z) FMA_ROW(7, a1.w)
  }
  __syncthreads();
  if (colbase + 64 <= outColLim) {
    #pragma unroll
    for (int i = 0; i < 8; ++i) {
      int row = rowbase + ty * 8 + i;
      float4 st; st.x = acc[i][0]; st.y = acc[i][1]; st.z = acc[i][2]; st.w = acc[i][3];
      *(float4*)(outp + (size_t)row * outld + outcol0 + colbase + tx * 4) = st;
    }
  } else {
    #pragma unroll
    for (int i = 0; i < 8; ++i) {
      int row = rowbase + ty * 8 + i;
      #pragma unroll
      for (int j = 0; j < 4; ++j) {
        int c = colbase + tx * 4 + j;
        if (c < outColLim) outp[(size_t)row * outld + outcol0 + c] = acc[i][j];
      }
    }
  }
}

// chain stage: squares (splitK8 -> 8 P planes) | extends (splitK8 -> 8 V planes)
//              | wtilde filler | stats filler | reduceV cols 0..511 filler (stage 9)
template<int ANP>
__global__ __launch_bounds__(256) void k_chain(const float* __restrict__ Pc,
                                               float* __restrict__ Pn,
                                               float* __restrict__ Vp,
                                               int m, int nSq, int ntct,
                                               const float* __restrict__ wre,
                                               const float* __restrict__ wim,
                                               const float* __restrict__ epart,
                                               float* __restrict__ wt_re,
                                               float* __restrict__ wt_im,
                                               int wstart, int wcount,
                                               const float* __restrict__ x,
                                               float* __restrict__ means,
                                               float* __restrict__ stdev,
                                               int statCount, int redCount,
                                               float* __restrict__ V) {
  __shared__ float smem[6608];
  float* As = smem;            // [32][132]
  float* Bs = smem + 4224;     // [32][68]
  const int blk = blockIdx.x;
  const int t = threadIdx.x;
  const int nExt = 48 * ntct;  // 8 slices x 2 rt x ntct x 3 s
  const int b0 = nSq + nExt;
  if (blk < nSq) {
    int slice = blk & 7, rest = blk >> 3;
    int t8 = rest & 7, s = rest >> 3;
    int rt = t8 & 1, ct = t8 >> 1;
    const float* Ab = Pc + (size_t)s * 65536;
    gemm32<ANP, ANP>(As, Bs, Ab, PSTR, Ab, PSTR, 256, 256,
           rt * 128, ct * 64, slice * 32,
           Pn + (size_t)slice * PSTR + (size_t)s * 65536, 256, 0, 256);
  } else if (blk < b0) {
    int e = blk - nSq;
    int slice = e & 7, rt = (e >> 3) & 1, rest2 = e >> 4;
    int ct = rest2 % ntct, s = rest2 / ntct;
    gemm32<ANP, NPL>(As, Bs, Pc + (size_t)s * 65536, PSTR,
           Vp + (size_t)s * 262144, VPSTR, 1024, m,
           rt * 128, ct * 64, slice * 32,
           Vp + (size_t)slice * VPSTR + (size_t)s * 262144, 1024, m, m);
  } else if (blk < b0 + wcount) {
    wtilde_task(wstart + (blk - b0), smem, wre, wim, epart, wt_re, wt_im);
  } else if (blk < b0 + wcount + statCount) {
    int bc = blk - b0 - wcount;
    int b = bc / NC, c = bc % NC;
    float* xs = smem;
    float* red = smem + 1024;
    for (int e = 0; e < 4; ++e) {
      int tau = t + 256 * e;
      xs[tau] = x[((size_t)b * LSEQ + tau) * NC + c];
    }
    __syncthreads();
    float p = 0.f;
    for (int e = 0; e < 4; ++e) p += xs[t + 256 * e];
    float sum = block_reduce_sum(p, red);
    float mean = sum * (1.0f / LSEQ);
    float q = 0.f;
    for (int e = 0; e < 4; ++e) { float d = xs[t + 256 * e] - mean; q += d * d; }
    float sq = block_reduce_sum(q, red);
    if (t == 0) {
      means[bc] = mean;
      stdev[bc] = sqrtf(sq * (1.0f / LSEQ) + 1e-5f);
    }
  } else if (blk < b0 + wcount + statCount + redCount) {
    int rid = blk - b0 - wcount - statCount;   // row 0..767; cols 0..511 final after stage 8
    for (int e = 0; e < 2; ++e) {
      size_t idx = (size_t)rid * 1024 + e * 256 + t;
      float v = 0.f;
      #pragma unroll
      for (int pl = 0; pl < NPL; ++pl) v += Vp[(size_t)pl * VPSTR + idx];
      V[idx] = v;
    }
  }
}

// collapse planes for cols 512..1023 (written by stage 9)
__global__ __launch_bounds__(256) void k_reduceV2(const float* __restrict__ Vp,
                                                  float* __restrict__ V) {
  int t = threadIdx.x;
  for (int e = 0; e < 2; ++e) {
    size_t idx = (size_t)blockIdx.x * 1024 + 512 + e * 256 + t;
    float v = 0.f;
    #pragma unroll
    for (int pl = 0; pl < NPL; ++pl) v += Vp[(size_t)pl * VPSTR + idx];
    V[idx] = v;
  }
}

// fused: ut row (s,k) -> twiddle -> in-LDS prefix scan -> atomic H contribution
__global__ __launch_bounds__(256) void k_utscan(const float* __restrict__ wt_re,
                                                const float* __restrict__ wt_im,
                                                const float* __restrict__ V,
                                                const float* __restrict__ w_mlp,
                                                float* __restrict__ H) {
  int blk = blockIdx.x;   // s*NM + k
  int s = blk / NM, k = blk & 31;
  int t = threadIdx.x;
  __shared__ float sr[LSEQ], si_[LSEQ];
  __shared__ float cr[256], ci[256];
  const float* wr = wt_re + (size_t)blk * NH;
  const float* wi_ = wt_im + (size_t)blk * NH;
  const float* Vs = V + (size_t)s * NH * LSEQ;
  float ar[4] = {0.f, 0.f, 0.f, 0.f}, ai[4] = {0.f, 0.f, 0.f, 0.f};
  for (int i = 0; i < NH; ++i) {
    float a = wr[i], b = wi_[i];
    const float* vrow = Vs + (size_t)i * LSEQ + t;
    #pragma unroll
    for (int e = 0; e < 4; ++e) {
      float v = vrow[256 * e];
      ar[e] += a * v; ai[e] += b * v;
    }
  }
  for (int e = 0; e < 4; ++e) {
    int d = t + 256 * e;
    int frac = (k * d) & 1023;
    float ang = -(TWO_PI / 1024.0f) * (float)frac;
    float sn, csn; sincosf(ang, &sn, &csn);
    sr[d] = ar[e] * csn - ai[e] * sn;
    si_[d] = ar[e] * sn + ai[e] * csn;
  }
  __syncthreads();
  float lr[4], li[4], rr = 0.f, ii = 0.f;
  for (int e = 0; e < 4; ++e) {
    rr += sr[4 * t + e]; ii += si_[4 * t + e];
    lr[e] = rr; li[e] = ii;
  }
  cr[t] = rr; ci[t] = ii;
  __syncthreads();
  for (int off = 1; off < 256; off <<= 1) {
    float pr = 0.f, pi = 0.f;
    if (t >= off) { pr = cr[t - off]; pi = ci[t - off]; }
    __syncthreads();
    cr[t] += pr; ci[t] += pi;
    __syncthreads();
  }
  float offr = (t > 0) ? cr[t - 1] : 0.0f;
  float offi = (t > 0) ? ci[t - 1] : 0.0f;
  for (int e = 0; e < 4; ++e) {
    sr[4 * t + e] = lr[e] + offr;
    si_[4 * t + e] = li[e] + offi;
  }
  __syncthreads();
  float wm = w_mlp[s];
  float coef = wm * ((k == 0) ? 1.0f : 2.0f) * (1.0f / LSEQ);
  for (int e = 0; e < 4; ++e) {
    int tau = t + 256 * e;
    int mIdx = 1023 - tau;
    int frac = (k * (tau + 1)) & 1023;
    float ang = -(TWO_PI / 1024.0f) * (float)frac;
    float sn, csn; sincosf(ang, &sn, &csn);
    float val = coef * (sr[mIdx] * csn - si_[mIdx] * sn);
    atomicAdd(&H[tau], val);
  }
}

// feat per (b,c) + atomic accumulate into out (pre-initialized to b_fc)
__global__ __launch_bounds__(256) void k_feat(const float* __restrict__ x,
                                              const float* __restrict__ means,
                                              const float* __restrict__ stdev,
                                              const float* __restrict__ aw,
                                              const float* __restrict__ ab,
                                              const float* __restrict__ b_mlp,
                                              const float* __restrict__ H,
                                              const float* __restrict__ w_fc,
                                              float* __restrict__ out) {
  int bc = blockIdx.x; int b = bc / NC, c = bc % NC;
  __shared__ float red[256];
  int t = threadIdx.x;
  float mn = means[bc], sd = stdev[bc];
  float w = aw[c], bb = ab[c];
  float acc = 0.f;
  for (int e = 0; e < 4; ++e) {
    int tau = t + 256 * e;
    float xv = x[((size_t)b * LSEQ + tau) * NC + c];
    float f = (xv - mn) / sd * w + bb;
    acc += f * H[tau];
  }
  float sum = block_reduce_sum(acc, red);
  if (t == 0) {
    float mr = sum + b_mlp[0];
    float featv = (mr - bb) / (w + 1e-10f) * sd + mn;
    #pragma unroll
    for (int d = 0; d < 5; ++d)
      atomicAdd(&out[b * 5 + d], featv * w_fc[d * NC + c]);
  }
}

extern "C" void kernel_launch(void* const* d_in, const int* in_sizes, int n_in,
                              void* d_out, int out_size, void* d_ws, size_t ws_size,
                              hipStream_t stream) {
  const float* x_enc   = (const float*)d_in[0];
  const float* aw      = (const float*)d_in[1];
  const float* ab      = (const float*)d_in[2];
  const float* wre     = (const float*)d_in[3];
  const float* wim     = (const float*)d_in[4];
  const float* w_mlp   = (const float*)d_in[5];
  const float* b_mlp   = (const float*)d_in[6];
  const float* w_fc    = (const float*)d_in[7];
  const float* b_fc    = (const float*)d_in[8];
  const float* A_mats  = (const float*)d_in[9];
  const float* B_vecs  = (const float*)d_in[10];
  const float* ev      = (const float*)d_in[11];

  float* ws    = (float*)d_ws;
  float* means = ws + OFF_MEANS;
  float* stdev = ws + OFF_STDEV;
  float* epart = ws + OFF_EPART;
  float* wt_re = ws + OFF_WT_RE;
  float* wt_im = ws + OFF_WT_IM;
  float* Vp    = ws + OFF_VP;
  float* V     = ws + OFF_V;
  float* PP0   = ws + OFF_PP0;
  float* PP1   = ws + OFF_PP1;
  float* H     = ws + OFF_H;
  float* out   = (float*)d_out;

  k_front<<<98, 256, 0, stream>>>(B_vecs, ev, b_fc, epart, Vp, H, out);

  static const int wst[5] = {0, 154, 308, 462, 616};
  static const int wcn[5] = {154, 154, 154, 154, 152};
  const float* Pc = A_mats;
  float* Pn = PP0;
  for (int si = 0; si < 10; ++si) {
    int m = 1 << si;
    int doSq = (si < 9);
    int nSq = doSq ? 192 : 0;
    int ntct = (m + 63) >> 6;
    int wstart = (si < 5) ? wst[si] : 0;
    int wcount = (si < 5) ? wcn[si] : 0;
    int statCount = (si == 0) ? 192 : 0;
    int redCount = (si == 9) ? 768 : 0;
    int grid = nSq + 48 * ntct + wcount + statCount + redCount;
    if (si == 0)
      k_chain<1><<<grid, 256, 0, stream>>>(Pc, Pn, Vp, m, nSq, ntct,
          wre, wim, epart, wt_re, wt_im, wstart, wcount,
          x_enc, means, stdev, statCount, redCount, V);
    else
      k_chain<NPL><<<grid, 256, 0, stream>>>(Pc, Pn, Vp, m, nSq, ntct,
          wre, wim, epart, wt_re, wt_im, wstart, wcount,
          x_enc, means, stdev, statCount, redCount, V);
    if (doSq) { Pc = Pn; Pn = (Pn == PP0) ? PP1 : PP0; }
  }

  k_reduceV2<<<768, 256, 0, stream>>>(Vp, V);
  k_utscan<<<NS * NM, 256, 0, stream>>>(wt_re, wt_im, V, w_mlp, H);
  k_feat<<<192, 256, 0, stream>>>(x_enc, means, stdev, aw, ab, b_mlp, H, w_fc, out);
}

// Round 11
// 161.211 us; speedup vs baseline: 3.5803x; 1.0721x over previous
//
#include <hip/hip_runtime.h>
#include <math.h>

#define LSEQ 1024
#define NB 16
#define NC 12
#define NH 256
#define NM 32
#define NS 3
#define TWO_PI 6.283185307179586f

#define NPL   8          // split-K planes
#define PSTR  196608     // P plane stride (3*256*256)
#define VPSTR 786432     // V plane stride (3*256*1024)

// ---- workspace layout (float offsets) ----
#define OFF_MEANS 0            // 192
#define OFF_STDEV 192          // 192
#define OFF_EPART 384          // 24576
#define OFF_WT_RE 24960        // 24576
#define OFF_WT_IM 49536        // 24576
#define OFF_VP    74112        // 8 planes x 786432 = 6291456
#define OFF_V     6365568      // 786432 (dense)
#define OFF_PP0   7152000      // 8 planes x 196608 = 1572864
#define OFF_PP1   8724864      // 1572864
#define OFF_H     10297728     // 1024

__device__ __forceinline__ float block_reduce_sum(float v, float* sbuf) {
  int t = threadIdx.x;
  sbuf[t] = v; __syncthreads();
  for (int off = 128; off > 0; off >>= 1) {
    if (t < off) sbuf[t] += sbuf[t + off];
    __syncthreads();
  }
  float r = sbuf[0];
  __syncthreads();
  return r;
}

// float4 wtilde task for one (s,i): wt[s,k,i] = sum_o ebar[s,o]*w[s,i,o,k]
__device__ __forceinline__ void wtilde_task(int w, float* smem,
                                            const float* __restrict__ wre,
                                            const float* __restrict__ wim,
                                            const float* __restrict__ epart,
                                            float* __restrict__ wt_re,
                                            float* __restrict__ wt_im) {
  int s = w >> 8, i = w & 255;
  int t = threadIdx.x;
  float* ebs = smem;
  float* sr  = smem + 256;
  float* si2 = smem + 1280;
  float eb = 0.f;
  for (int ch = 0; ch < 32; ++ch) eb += epart[(s * 32 + ch) * 256 + t];
  ebs[t] = eb * (1.0f / LSEQ);
  __syncthreads();
  const float* br = wre + (size_t)(s * NH + i) * NH * NM;
  const float* bi = wim + (size_t)(s * NH + i) * NH * NM;
  float aR[4] = {0.f, 0.f, 0.f, 0.f}, aI[4] = {0.f, 0.f, 0.f, 0.f};
  #pragma unroll
  for (int it = 0; it < 8; ++it) {
    int o = (t >> 3) + 32 * it;
    float e = ebs[o];
    float4 vr = *(const float4*)(br + (size_t)t * 4 + 1024 * it);
    float4 vi = *(const float4*)(bi + (size_t)t * 4 + 1024 * it);
    aR[0] += e * vr.x; aR[1] += e * vr.y; aR[2] += e * vr.z; aR[3] += e * vr.w;
    aI[0] += e * vi.x; aI[1] += e * vi.y; aI[2] += e * vi.z; aI[3] += e * vi.w;
  }
  *(float4*)(sr + t * 4)  = make_float4(aR[0], aR[1], aR[2], aR[3]);
  *(float4*)(si2 + t * 4) = make_float4(aI[0], aI[1], aI[2], aI[3]);
  __syncthreads();
  if (t < 32) {
    float r = 0.f, im = 0.f;
    #pragma unroll
    for (int og = 0; og < 32; ++og) { r += sr[og * 32 + t]; im += si2[og * 32 + t]; }
    wt_re[(size_t)(s * NM + t) * NH + i] = r;
    wt_im[(size_t)(s * NM + t) * NH + i] = im;
  }
  __syncthreads();
}

#define FMA_ROW(r, av) { acc[r][0] += (av)*b4.x; acc[r][1] += (av)*b4.y; acc[r][2] += (av)*b4.z; acc[r][3] += (av)*b4.w; }

// 128x64 output tile, single K-slice of 32 (one barrier round). 8x4 acc/thread.
template<int ANP, int BNP>
__device__ __forceinline__ void gemm32(float* As, float* Bs,
                       const float* Abase, int apstr,
                       const float* Bbase, int bpstr, int bld, int colLimit,
                       int rowbase, int colbase, int kb,
                       float* outp, int outld, int outcol0, int outColLim) {
  const int tid = threadIdx.x;
  const int tx = tid & 15, ty = tid >> 4;
  const int kkA = tid & 31, rA = tid >> 5;
  const int jB = tid & 63, kB = tid >> 6;
  float acc[8][4];
  #pragma unroll
  for (int i = 0; i < 8; ++i)
    #pragma unroll
    for (int j = 0; j < 4; ++j) acc[i][j] = 0.f;

  #pragma unroll
  for (int p = 0; p < 16; ++p) {
    int row = rowbase + rA + 8 * p;
    float pv[ANP];
    #pragma unroll
    for (int pp = 0; pp < ANP; ++pp)
      pv[pp] = Abase[(size_t)pp * apstr + (size_t)row * 256 + kb + kkA];
    float v = pv[0];
    #pragma unroll
    for (int pp = 1; pp < ANP; ++pp) v += pv[pp];
    As[kkA * 132 + rA + 8 * p] = v;
  }
  #pragma unroll
  for (int q = 0; q < 8; ++q) {
    int kk = kB + 4 * q;
    int j = colbase + jB;
    float v = 0.f;
    if (j < colLimit) {
      float pv[BNP];
      #pragma unroll
      for (int pp = 0; pp < BNP; ++pp)
        pv[pp] = Bbase[(size_t)pp * bpstr + (size_t)(kb + kk) * bld + j];
      v = pv[0];
      #pragma unroll
      for (int pp = 1; pp < BNP; ++pp) v += pv[pp];
    }
    Bs[kk * 68 + jB] = v;
  }
  __syncthreads();
  #pragma unroll
  for (int kk = 0; kk < 32; ++kk) {
    float4 b4 = *(const float4*)(Bs + kk * 68 + tx * 4);
    float4 a0 = *(const float4*)(As + kk * 132 + ty * 8);
    float4 a1 = *(const float4*)(As + kk * 132 + ty * 8 + 4);
    FMA_ROW(0, a0.x) FMA_ROW(1, a0.y) FMA_ROW(2, a0.z) FMA_ROW(3, a0.w)
    FMA_ROW(4, a1.x) FMA_ROW(5, a1.y) FMA_ROW(6, a1.z) FMA_ROW(7, a1.w)
  }
  __syncthreads();
  if (colbase + 64 <= outColLim) {
    #pragma unroll
    for (int i = 0; i < 8; ++i) {
      int row = rowbase + ty * 8 + i;
      float4 st; st.x = acc[i][0]; st.y = acc[i][1]; st.z = acc[i][2]; st.w = acc[i][3];
      *(float4*)(outp + (size_t)row * outld + outcol0 + colbase + tx * 4) = st;
    }
  } else {
    #pragma unroll
    for (int i = 0; i < 8; ++i) {
      int row = rowbase + ty * 8 + i;
      #pragma unroll
      for (int j = 0; j < 4; ++j) {
        int c = colbase + tx * 4 + j;
        if (c < outColLim) outp[(size_t)row * outld + outcol0 + c] = acc[i][j];
      }
    }
  }
}

// chain stage: squares | extends | wtilde | stats | reduceV(0..511) | epart | V01 | H/out init
template<int ANP>
__global__ __launch_bounds__(256) void k_chain(const float* __restrict__ Pc,
                                               float* __restrict__ Pn,
                                               float* __restrict__ Vp,
                                               int m, int nSq, int ntct,
                                               const float* __restrict__ wre,
                                               const float* __restrict__ wim,
                                               const float* __restrict__ epart_c,
                                               float* __restrict__ wt_re,
                                               float* __restrict__ wt_im,
                                               int wstart, int wcount,
                                               const float* __restrict__ x,
                                               float* __restrict__ means,
                                               float* __restrict__ stdev,
                                               int statCount, int redCount,
                                               float* __restrict__ V,
                                               const float* __restrict__ ev,
                                               float* __restrict__ epart_w,
                                               int epCount,
                                               const float* __restrict__ Bv,
                                               int v01Count,
                                               const float* __restrict__ b_fc,
                                               float* __restrict__ H,
                                               float* __restrict__ out,
                                               int hCount) {
  __shared__ float smem[6608];
  float* As = smem;            // [32][132]
  float* Bs = smem + 4224;     // [32][68]
  const int blk = blockIdx.x;
  const int t = threadIdx.x;
  const int nExt = 48 * ntct;
  const int b0 = nSq + nExt;
  const int b1 = b0 + wcount;
  const int b2 = b1 + statCount;
  const int b3 = b2 + redCount;
  const int b4_ = b3 + epCount;
  const int b5 = b4_ + v01Count;
  if (blk < nSq) {
    int slice = blk & 7, rest = blk >> 3;
    int t8 = rest & 7, s = rest >> 3;
    int rt = t8 & 1, ct = t8 >> 1;
    const float* Ab = Pc + (size_t)s * 65536;
    gemm32<ANP, ANP>(As, Bs, Ab, PSTR, Ab, PSTR, 256, 256,
           rt * 128, ct * 64, slice * 32,
           Pn + (size_t)slice * PSTR + (size_t)s * 65536, 256, 0, 256);
  } else if (blk < b0) {
    int e = blk - nSq;
    int slice = e & 7, rt = (e >> 3) & 1, rest2 = e >> 4;
    int ct = rest2 % ntct, s = rest2 / ntct;
    gemm32<ANP, NPL>(As, Bs, Pc + (size_t)s * 65536, PSTR,
           Vp + (size_t)s * 262144, VPSTR, 1024, m,
           rt * 128, ct * 64, slice * 32,
           Vp + (size_t)slice * VPSTR + (size_t)s * 262144, 1024, m, m);
  } else if (blk < b1) {
    wtilde_task(wstart + (blk - b0), smem, wre, wim, epart_c, wt_re, wt_im);
  } else if (blk < b2) {
    int bc = blk - b1;
    int b = bc / NC, c = bc % NC;
    float* xs = smem;
    float* red = smem + 1024;
    for (int e = 0; e < 4; ++e) {
      int tau = t + 256 * e;
      xs[tau] = x[((size_t)b * LSEQ + tau) * NC + c];
    }
    __syncthreads();
    float p = 0.f;
    for (int e = 0; e < 4; ++e) p += xs[t + 256 * e];
    float sum = block_reduce_sum(p, red);
    float mean = sum * (1.0f / LSEQ);
    float q = 0.f;
    for (int e = 0; e < 4; ++e) { float d = xs[t + 256 * e] - mean; q += d * d; }
    float sq = block_reduce_sum(q, red);
    if (t == 0) {
      means[bc] = mean;
      stdev[bc] = sqrtf(sq * (1.0f / LSEQ) + 1e-5f);
    }
  } else if (blk < b3) {
    int rid = blk - b2;   // row 0..767; cols 0..511 final after stage 8
    for (int e = 0; e < 2; ++e) {
      size_t idx = (size_t)rid * 1024 + e * 256 + t;
      float v = 0.f;
      #pragma unroll
      for (int pl = 0; pl < NPL; ++pl) v += Vp[(size_t)pl * VPSTR + idx];
      V[idx] = v;
    }
  } else if (blk < b4_) {
    int bb = blk - b3;           // s*32 + chunk
    int s = bb >> 5, ch = bb & 31;
    float acc = 0.f;
    const float* base = ev + (size_t)s * LSEQ * NH + (size_t)ch * 32 * NH + t;
    for (int l = 0; l < 32; ++l) acc += base[(size_t)l * NH];
    epart_w[(size_t)bb * NH + t] = acc;
  } else if (blk < b5) {
    // V01: col0 = B, col1 = A*B (plane 0); zero planes 1..7 cols 0..1
    int v = blk - b4_;           // 0..5
    int s = v >> 1, half = v & 1;
    float* bsh = smem;           // 256
    float* psh = smem + 256;     // 256
    bsh[t] = Bv[s * 256 + t];
    __syncthreads();
    int i = half * 128 + (t >> 1);
    int k2 = (t & 1) * 128;
    const float* Arow = Pc + (size_t)s * 65536 + (size_t)i * 256 + k2;
    float acc = 0.f;
    for (int kk = 0; kk < 128; ++kk) acc += Arow[kk] * bsh[k2 + kk];
    psh[t] = acc;
    __syncthreads();
    if ((t & 1) == 0) {
      int row = s * 256 + i;
      Vp[(size_t)row * 1024 + 1] = psh[t] + psh[t + 1];
      Vp[(size_t)row * 1024] = bsh[i];
    }
    for (int z = t; z < 7 * 128 * 2; z += 256) {
      int pl = 1 + (z >> 8);
      int rr2 = (z >> 1) & 127;
      int col = z & 1;
      int row = s * 256 + half * 128 + rr2;
      Vp[(size_t)pl * VPSTR + (size_t)row * 1024 + col] = 0.f;
    }
  } else if (blk < b5 + hCount) {
    for (int e = 0; e < 4; ++e) H[t + 256 * e] = 0.0f;
    if (t < NB * 5) out[t] = b_fc[t % 5];
  }
}

// collapse planes for cols 512..1023 (written by stage 9)
__global__ __launch_bounds__(256) void k_reduceV2(const float* __restrict__ Vp,
                                                  float* __restrict__ V) {
  int t = threadIdx.x;
  for (int e = 0; e < 2; ++e) {
    size_t idx = (size_t)blockIdx.x * 1024 + 512 + e * 256 + t;
    float v = 0.f;
    #pragma unroll
    for (int pl = 0; pl < NPL; ++pl) v += Vp[(size_t)pl * VPSTR + idx];
    V[idx] = v;
  }
}

// fused: ut row (s,k) via float4 V reads -> twiddle -> scan -> atomic H contribution
__global__ __launch_bounds__(256) void k_utscan(const float* __restrict__ wt_re,
                                                const float* __restrict__ wt_im,
                                                const float* __restrict__ V,
                                                const float* __restrict__ w_mlp,
                                                float* __restrict__ H) {
  int blk = blockIdx.x;   // s*NM + k
  int s = blk / NM, k = blk & 31;
  int t = threadIdx.x;
  __shared__ float sr[LSEQ], si_[LSEQ];
  __shared__ float cr[256], ci[256];
  const float* wr = wt_re + (size_t)blk * NH;
  const float* wi_ = wt_im + (size_t)blk * NH;
  const float* Vs = V + (size_t)s * NH * LSEQ;
  float ar[4] = {0.f, 0.f, 0.f, 0.f}, ai[4] = {0.f, 0.f, 0.f, 0.f};
  for (int i = 0; i < NH; ++i) {
    float a = wr[i], b = wi_[i];
    float4 v4 = *(const float4*)(Vs + (size_t)i * LSEQ + 4 * t);
    ar[0] += a * v4.x; ai[0] += b * v4.x;
    ar[1] += a * v4.y; ai[1] += b * v4.y;
    ar[2] += a * v4.z; ai[2] += b * v4.z;
    ar[3] += a * v4.w; ai[3] += b * v4.w;
  }
  // twiddle + local serial scan in registers (d = 4t+e)
  float lr[4], li[4], rr = 0.f, ii = 0.f;
  #pragma unroll
  for (int e = 0; e < 4; ++e) {
    int d = 4 * t + e;
    int frac = (k * d) & 1023;
    float ang = -(TWO_PI / 1024.0f) * (float)frac;
    float sn, csn; sincosf(ang, &sn, &csn);
    float tr = ar[e] * csn - ai[e] * sn;
    float ti = ar[e] * sn + ai[e] * csn;
    rr += tr; ii += ti;
    lr[e] = rr; li[e] = ii;
  }
  cr[t] = rr; ci[t] = ii;
  __syncthreads();
  for (int off = 1; off < 256; off <<= 1) {
    float pr = 0.f, pi = 0.f;
    if (t >= off) { pr = cr[t - off]; pi = ci[t - off]; }
    __syncthreads();
    cr[t] += pr; ci[t] += pi;
    __syncthreads();
  }
  float offr = (t > 0) ? cr[t - 1] : 0.0f;
  float offi = (t > 0) ? ci[t - 1] : 0.0f;
  #pragma unroll
  for (int e = 0; e < 4; ++e) {
    sr[4 * t + e] = lr[e] + offr;
    si_[4 * t + e] = li[e] + offi;
  }
  __syncthreads();
  float wm = w_mlp[s];
  float coef = wm * ((k == 0) ? 1.0f : 2.0f) * (1.0f / LSEQ);
  for (int e = 0; e < 4; ++e) {
    int tau = t + 256 * e;
    int mIdx = 1023 - tau;
    int frac = (k * (tau + 1)) & 1023;
    float ang = -(TWO_PI / 1024.0f) * (float)frac;
    float sn, csn; sincosf(ang, &sn, &csn);
    float val = coef * (sr[mIdx] * csn - si_[mIdx] * sn);
    atomicAdd(&H[tau], val);
  }
}

// feat per (b,c) + atomic accumulate into out (pre-initialized to b_fc)
__global__ __launch_bounds__(256) void k_feat(const float* __restrict__ x,
                                              const float* __restrict__ means,
                                              const float* __restrict__ stdev,
                                              const float* __restrict__ aw,
                                              const float* __restrict__ ab,
                                              const float* __restrict__ b_mlp,
                                              const float* __restrict__ H,
                                              const float* __restrict__ w_fc,
                                              float* __restrict__ out) {
  int bc = blockIdx.x; int b = bc / NC, c = bc % NC;
  __shared__ float red[256];
  int t = threadIdx.x;
  float mn = means[bc], sd = stdev[bc];
  float w = aw[c], bb = ab[c];
  float acc = 0.f;
  for (int e = 0; e < 4; ++e) {
    int tau = t + 256 * e;
    float xv = x[((size_t)b * LSEQ + tau) * NC + c];
    float f = (xv - mn) / sd * w + bb;
    acc += f * H[tau];
  }
  float sum = block_reduce_sum(acc, red);
  if (t == 0) {
    float mr = sum + b_mlp[0];
    float featv = (mr - bb) / (w + 1e-10f) * sd + mn;
    #pragma unroll
    for (int d = 0; d < 5; ++d)
      atomicAdd(&out[b * 5 + d], featv * w_fc[d * NC + c]);
  }
}

extern "C" void kernel_launch(void* const* d_in, const int* in_sizes, int n_in,
                              void* d_out, int out_size, void* d_ws, size_t ws_size,
                              hipStream_t stream) {
  const float* x_enc   = (const float*)d_in[0];
  const float* aw      = (const float*)d_in[1];
  const float* ab      = (const float*)d_in[2];
  const float* wre     = (const float*)d_in[3];
  const float* wim     = (const float*)d_in[4];
  const float* w_mlp   = (const float*)d_in[5];
  const float* b_mlp   = (const float*)d_in[6];
  const float* w_fc    = (const float*)d_in[7];
  const float* b_fc    = (const float*)d_in[8];
  const float* A_mats  = (const float*)d_in[9];
  const float* B_vecs  = (const float*)d_in[10];
  const float* ev      = (const float*)d_in[11];

  float* ws    = (float*)d_ws;
  float* means = ws + OFF_MEANS;
  float* stdev = ws + OFF_STDEV;
  float* epart = ws + OFF_EPART;
  float* wt_re = ws + OFF_WT_RE;
  float* wt_im = ws + OFF_WT_IM;
  float* Vp    = ws + OFF_VP;
  float* V     = ws + OFF_V;
  float* PP0   = ws + OFF_PP0;
  float* PP1   = ws + OFF_PP1;
  float* H     = ws + OFF_H;
  float* out   = (float*)d_out;

  static const int wcn[5] = {154, 154, 154, 154, 152};
  static const int wst[5] = {0, 154, 308, 462, 616};
  const float* Pc = A_mats;
  float* Pn = PP0;
  for (int si = 0; si < 10; ++si) {
    int m = 1 << si;
    int doSq = (si < 9);
    int nSq = doSq ? 192 : 0;
    int ntct = (si == 0) ? 0 : ((m + 63) >> 6);
    int wstart = (si >= 1 && si <= 5) ? wst[si - 1] : 0;
    int wcount = (si >= 1 && si <= 5) ? wcn[si - 1] : 0;
    int statCount = (si == 0) ? 192 : 0;
    int redCount = (si == 9) ? 768 : 0;
    int epCount = (si == 0) ? 96 : 0;
    int v01Count = (si == 0) ? 6 : 0;
    int hCount = (si == 0) ? 1 : 0;
    int grid = nSq + 48 * ntct + wcount + statCount + redCount + epCount + v01Count + hCount;
    if (si == 0)
      k_chain<1><<<grid, 256, 0, stream>>>(Pc, Pn, Vp, m, nSq, ntct,
          wre, wim, epart, wt_re, wt_im, wstart, wcount,
          x_enc, means, stdev, statCount, redCount, V,
          ev, epart, epCount, B_vecs, v01Count, b_fc, H, out, hCount);
    else
      k_chain<NPL><<<grid, 256, 0, stream>>>(Pc, Pn, Vp, m, nSq, ntct,
          wre, wim, epart, wt_re, wt_im, wstart, wcount,
          x_enc, means, stdev, statCount, redCount, V,
          ev, epart, epCount, B_vecs, v01Count, b_fc, H, out, hCount);
    if (doSq) { Pc = Pn; Pn = (Pn == PP0) ? PP1 : PP0; }
  }

  k_reduceV2<<<768, 256, 0, stream>>>(Vp, V);
  k_utscan<<<NS * NM, 256, 0, stream>>>(wt_re, wt_im, V, w_mlp, H);
  k_feat<<<192, 256, 0, stream>>>(x_enc, means, stdev, aw, ab, b_mlp, H, w_fc, out);
}